// Round 8
// baseline (746.391 us; speedup 1.0000x reference)
//
#include <hip/hip_runtime.h>
#include <hip/hip_bf16.h>

#define BB 8
#define TT 1024
#define DD 1024
#define HH 16
#define DH 64
#define QKVLD 3072

typedef __attribute__((ext_vector_type(8))) short short8;
typedef __attribute__((ext_vector_type(4))) float f32x4;

__device__ __forceinline__ unsigned short f2bf(float f) {
  unsigned int u = __builtin_bit_cast(unsigned int, f);
  unsigned int rounding = 0x7fffu + ((u >> 16) & 1u);
  u += rounding;
  return (unsigned short)(u >> 16);
}

__device__ __forceinline__ void gload16(const void* g, void* l) {
  __builtin_amdgcn_global_load_lds((const __attribute__((address_space(1))) void*)g,
                                   (__attribute__((address_space(3))) void*)l, 16, 0, 0);
}

// ---- fused f32 -> bf16 TRANSPOSING convert of all 4 weights: out[n][k] = bf16(in[k][n]) ----
__global__ __launch_bounds__(256) void convertT4_k(const float* __restrict__ w0,
                                                   const float* __restrict__ w1,
                                                   const float* __restrict__ w2,
                                                   const float* __restrict__ w3,
                                                   unsigned short* __restrict__ out) {
  int bx = blockIdx.x;
  int seg = bx >> 9;
  const float* in = seg == 0 ? w0 : seg == 1 ? w1 : seg == 2 ? w2 : w3;
  unsigned short* o = out + (size_t)seg * DD * DD;
  int g = (bx & 511) * 256 + threadIdx.x;
  int n = g & (DD - 1);
  int kb = (g >> 10) * 8;
  short8 v;
#pragma unroll
  for (int j = 0; j < 8; ++j) v[j] = (short)f2bf(in[(size_t)(kb + j) * DD + n]);
  *(short8*)(o + (size_t)n * DD + kb) = v;
}

// ---------------- fused QKV GEMM: [Q|K|V] = x @ W + b -> bf16 QKV[M][3072] ----------------
// Tile 128x128, BK=64. B staged via global_load_lds (linear dest, pre-swizzled src, swizzled read).
// A (f32) staged via VALU convert into padded LDS.
__global__ __launch_bounds__(256) void gemm_qkv_k(const float* __restrict__ Aq,
                                                  const float* __restrict__ Ak,
                                                  const float* __restrict__ Av,
                                                  const unsigned short* __restrict__ Wt3,
                                                  const float* __restrict__ bq,
                                                  const float* __restrict__ bk,
                                                  const float* __restrict__ bv,
                                                  unsigned short* __restrict__ C) {
  __shared__ unsigned short Bs[128 * 64];   // swizzled linear, 16KB
  __shared__ unsigned short As[128 * 72];   // padded, 18KB
  const int tid = threadIdx.x, lane = tid & 63, w = tid >> 6;
  const int lo = lane & 15, hi = lane >> 4;
  const int wm = w >> 1, wn = w & 1;
  const int seg = blockIdx.x >> 3;
  const float* Ap = seg == 0 ? Aq : seg == 1 ? Ak : Av;
  const float* bias = seg == 0 ? bq : seg == 1 ? bk : bv;
  const int n0 = blockIdx.x * 128;
  const int m0 = blockIdx.y * 128;
  f32x4 acc[4][4] = {};
  // DMA lane mapping: dest byte d -> logical (row n, k-byte) with XOR bits4-6 by row&7
  int dmn[4], dmk[4];
#pragma unroll
  for (int i = 0; i < 4; ++i) {
    int d = i * 4096 + w * 1024 + lane * 16;
    int lz = d ^ (((d >> 7) & 7) << 4);
    dmn[i] = d >> 7;
    dmk[i] = (lz & 127) >> 1;
  }
  for (int k0 = 0; k0 < DD; k0 += 64) {
#pragma unroll
    for (int i = 0; i < 4; ++i)
      gload16(Wt3 + (size_t)(n0 + dmn[i]) * DD + k0 + dmk[i], &Bs[(i * 4096 + w * 1024) >> 1]);
#pragma unroll
    for (int it = 0; it < 4; ++it) {
      int c = tid + 256 * it;
      int r = c >> 3, cb = (c & 7) * 8;
      const float* src = Ap + (size_t)(m0 + r) * DD + k0 + cb;
      float4 v0 = *(const float4*)src;
      float4 v1 = *(const float4*)(src + 4);
      short8 sv;
      sv[0] = (short)f2bf(v0.x); sv[1] = (short)f2bf(v0.y);
      sv[2] = (short)f2bf(v0.z); sv[3] = (short)f2bf(v0.w);
      sv[4] = (short)f2bf(v1.x); sv[5] = (short)f2bf(v1.y);
      sv[6] = (short)f2bf(v1.z); sv[7] = (short)f2bf(v1.w);
      *(short8*)&As[r * 72 + cb] = sv;
    }
    __syncthreads();
#pragma unroll
    for (int s = 0; s < 2; ++s) {
      short8 af[4], bf[4];
#pragma unroll
      for (int mt = 0; mt < 4; ++mt)
        af[mt] = *(const short8*)&As[(wm * 64 + mt * 16 + lo) * 72 + s * 32 + hi * 8];
#pragma unroll
      for (int nt = 0; nt < 4; ++nt) {
        int nr = wn * 64 + nt * 16 + lo;
        int byte = (nr * 128 + s * 64 + hi * 16) ^ ((nr & 7) << 4);
        bf[nt] = *(const short8*)((const char*)Bs + byte);
      }
#pragma unroll
      for (int mt = 0; mt < 4; ++mt)
#pragma unroll
        for (int nt = 0; nt < 4; ++nt)
          acc[mt][nt] = __builtin_amdgcn_mfma_f32_16x16x32_bf16(af[mt], bf[nt], acc[mt][nt], 0, 0, 0);
    }
    __syncthreads();
  }
#pragma unroll
  for (int mt = 0; mt < 4; ++mt)
#pragma unroll
    for (int nt = 0; nt < 4; ++nt) {
      int cl = wn * 64 + nt * 16 + lo;
      float bvv = bias[(n0 & 1023) + cl];
      int col = n0 + cl;
#pragma unroll
      for (int r = 0; r < 4; ++r) {
        int row = m0 + wm * 64 + mt * 16 + hi * 4 + r;
        C[(size_t)row * QKVLD + col] = f2bf(acc[mt][nt][r] + bvv);
      }
    }
}

// ---------------- output GEMM: out = Obf @ Wo + bo (f32 out), A and B both DMA-staged ----------------
__global__ __launch_bounds__(256) void gemm_out_k(const unsigned short* __restrict__ Aobf,
                                                  const unsigned short* __restrict__ WoT,
                                                  const float* __restrict__ bo,
                                                  float* __restrict__ out) {
  __shared__ unsigned short Bs[128 * 64];
  __shared__ unsigned short As[128 * 64];
  const int tid = threadIdx.x, lane = tid & 63, w = tid >> 6;
  const int lo = lane & 15, hi = lane >> 4;
  const int wm = w >> 1, wn = w & 1;
  const int n0 = blockIdx.x * 128;
  const int m0 = blockIdx.y * 128;
  f32x4 acc[4][4] = {};
  int dmn[4], dmk[4];
#pragma unroll
  for (int i = 0; i < 4; ++i) {
    int d = i * 4096 + w * 1024 + lane * 16;
    int lz = d ^ (((d >> 7) & 7) << 4);
    dmn[i] = d >> 7;
    dmk[i] = (lz & 127) >> 1;
  }
  for (int k0 = 0; k0 < DD; k0 += 64) {
#pragma unroll
    for (int i = 0; i < 4; ++i) {
      gload16(WoT + (size_t)(n0 + dmn[i]) * DD + k0 + dmk[i], &Bs[(i * 4096 + w * 1024) >> 1]);
      gload16(Aobf + (size_t)(m0 + dmn[i]) * DD + k0 + dmk[i], &As[(i * 4096 + w * 1024) >> 1]);
    }
    __syncthreads();
#pragma unroll
    for (int s = 0; s < 2; ++s) {
      short8 af[4], bf[4];
#pragma unroll
      for (int mt = 0; mt < 4; ++mt) {
        int mr = wm * 64 + mt * 16 + lo;
        int byte = (mr * 128 + s * 64 + hi * 16) ^ ((mr & 7) << 4);
        af[mt] = *(const short8*)((const char*)As + byte);
      }
#pragma unroll
      for (int nt = 0; nt < 4; ++nt) {
        int nr = wn * 64 + nt * 16 + lo;
        int byte = (nr * 128 + s * 64 + hi * 16) ^ ((nr & 7) << 4);
        bf[nt] = *(const short8*)((const char*)Bs + byte);
      }
#pragma unroll
      for (int mt = 0; mt < 4; ++mt)
#pragma unroll
        for (int nt = 0; nt < 4; ++nt)
          acc[mt][nt] = __builtin_amdgcn_mfma_f32_16x16x32_bf16(af[mt], bf[nt], acc[mt][nt], 0, 0, 0);
    }
    __syncthreads();
  }
#pragma unroll
  for (int mt = 0; mt < 4; ++mt)
#pragma unroll
    for (int nt = 0; nt < 4; ++nt) {
      int col = n0 + wn * 64 + nt * 16 + lo;
      float bvv = bo[col];
#pragma unroll
      for (int r = 0; r < 4; ++r) {
        int row = m0 + wm * 64 + mt * 16 + hi * 4 + r;
        out[(size_t)row * DD + col] = acc[mt][nt][r] + bvv;
      }
    }
}

// ------------- V transpose per head from QKV: -> (B,H,DH,T) -------------
__global__ __launch_bounds__(256) void transpose_v_k(const unsigned short* __restrict__ QKV,
                                                     unsigned short* __restrict__ Vt) {
  __shared__ unsigned short tile[64][72];
  const int blk = blockIdx.x;
  const int t0 = (blk & 15) * 64;
  const int h = (blk >> 4) & 15;
  const int b = blk >> 8;
  const int tid = threadIdx.x;
#pragma unroll
  for (int it = 0; it < 2; ++it) {
    int c = tid + 256 * it;
    int r = c >> 3, d8 = (c & 7) * 8;
    short8 v = *(const short8*)(QKV + ((size_t)(b * TT + t0 + r)) * QKVLD + 2048 + h * DH + d8);
    *(short8*)&tile[r][d8] = v;
  }
  __syncthreads();
#pragma unroll
  for (int it = 0; it < 2; ++it) {
    int c = tid + 256 * it;
    int d = c >> 3, t8 = (c & 7) * 8;
    short8 o;
#pragma unroll
    for (int j = 0; j < 8; ++j) o[j] = (short)tile[t8 + j][d];
    *(short8*)(Vt + ((size_t)(b * HH + h) * DH + d) * TT + t0 + t8) = o;
  }
}

// ---------------- flash attention, KVBLK=64 ----------------
// 4 waves; wave w owns 16 q-rows. P wave-private LDS (no block barriers).
__global__ __launch_bounds__(256) void attn_k(const unsigned short* __restrict__ QKV,
                                              const unsigned short* __restrict__ Vt,
                                              const float* __restrict__ spat,
                                              const float* __restrict__ edge,
                                              const int* __restrict__ mask,
                                              unsigned short* __restrict__ Obf) {
  __shared__ unsigned short P[4][16][72];
  const int blk = blockIdx.x;
  const int qt = blk & 15;
  const int h = (blk >> 4) & 15;
  const int b = blk >> 8;
  const int tid = threadIdx.x;
  const int w = tid >> 6;
  const int lane = tid & 63;
  const int lo = lane & 15, hi = lane >> 4;
  const int q0 = qt * 64 + w * 16;

  const unsigned short* Qb = QKV + ((size_t)(b * TT + q0)) * QKVLD + h * DH;
  const unsigned short* Kb = QKV + (size_t)b * TT * QKVLD + 1024 + h * DH;
  const unsigned short* Vb = Vt + (size_t)(b * HH + h) * DH * TT;
  const float* Sp = spat + (size_t)b * TT * TT;
  const float* Ed = edge + (size_t)b * TT * TT;
  const int* Mk = mask + b * TT;

  short8 qf0 = *(const short8*)(Qb + (size_t)lo * QKVLD + hi * 8);
  short8 qf1 = *(const short8*)(Qb + (size_t)lo * QKVLD + 32 + hi * 8);

  float m[4], l[4];
  f32x4 acc[4] = {};
#pragma unroll
  for (int r = 0; r < 4; ++r) { m[r] = -INFINITY; l[r] = 0.f; }

  for (int k0 = 0; k0 < TT; k0 += 64) {
    // issue all independent loads first: K frags + mask
    short8 kf[8];
#pragma unroll
    for (int kt = 0; kt < 4; ++kt) {
      const unsigned short* kp = Kb + (size_t)(k0 + kt * 16 + lo) * QKVLD + hi * 8;
      kf[kt * 2] = *(const short8*)kp;
      kf[kt * 2 + 1] = *(const short8*)(kp + 32);
    }
    int mk[4];
#pragma unroll
    for (int kt = 0; kt < 4; ++kt) mk[kt] = Mk[k0 + kt * 16 + lo];

    f32x4 sc[4];
#pragma unroll
    for (int kt = 0; kt < 4; ++kt) {
      f32x4 z = {};
      z = __builtin_amdgcn_mfma_f32_16x16x32_bf16(qf0, kf[kt * 2], z, 0, 0, 0);
      sc[kt] = __builtin_amdgcn_mfma_f32_16x16x32_bf16(qf1, kf[kt * 2 + 1], z, 0, 0, 0);
    }

    float alpha[4];
#pragma unroll
    for (int r = 0; r < 4; ++r) {
      const size_t roff = (size_t)(q0 + hi * 4 + r) * TT + k0;
      const float* srow = Sp + roff;
      const float* erow = Ed + roff;
      float s[4];
#pragma unroll
      for (int j = 0; j < 4; ++j) {
        float bb = mk[j] ? -1e30f : (srow[j * 16 + lo] + erow[j * 16 + lo]);
        s[j] = sc[j][r] * 0.125f + bb;
      }
      float mx = fmaxf(fmaxf(s[0], s[1]), fmaxf(s[2], s[3]));
      mx = fmaxf(mx, __shfl_xor(mx, 1));
      mx = fmaxf(mx, __shfl_xor(mx, 2));
      mx = fmaxf(mx, __shfl_xor(mx, 4));
      mx = fmaxf(mx, __shfl_xor(mx, 8));
      float mn = fmaxf(m[r], mx);
      alpha[r] = __expf(m[r] - mn);
      m[r] = mn;
      float rs = 0.f;
#pragma unroll
      for (int j = 0; j < 4; ++j) {
        s[j] = __expf(s[j] - mn);
        rs += s[j];
        P[w][hi * 4 + r][j * 16 + lo] = f2bf(s[j]);
      }
      rs += __shfl_xor(rs, 1);
      rs += __shfl_xor(rs, 2);
      rs += __shfl_xor(rs, 4);
      rs += __shfl_xor(rs, 8);
      l[r] = l[r] * alpha[r] + rs;
    }
#pragma unroll
    for (int dt = 0; dt < 4; ++dt)
#pragma unroll
      for (int r = 0; r < 4; ++r) acc[dt][r] *= alpha[r];

#pragma unroll
    for (int kc = 0; kc < 2; ++kc) {
      short8 pf = *(const short8*)&P[w][lo][kc * 32 + hi * 8];
#pragma unroll
      for (int dt = 0; dt < 4; ++dt) {
        short8 vf = *(const short8*)(Vb + (size_t)(dt * 16 + lo) * TT + k0 + kc * 32 + hi * 8);
        acc[dt] = __builtin_amdgcn_mfma_f32_16x16x32_bf16(pf, vf, acc[dt], 0, 0, 0);
      }
    }
  }

  float rl[4];
#pragma unroll
  for (int r = 0; r < 4; ++r) rl[r] = 1.0f / l[r];
  unsigned short* Ob = Obf + ((size_t)b * TT + q0) * DD + h * DH;
#pragma unroll
  for (int dt = 0; dt < 4; ++dt)
#pragma unroll
    for (int r = 0; r < 4; ++r)
      Ob[(size_t)(hi * 4 + r) * DD + dt * 16 + lo] = f2bf(acc[dt][r] * rl[r]);
}

extern "C" void kernel_launch(void* const* d_in, const int* in_sizes, int n_in,
                              void* d_out, int out_size, void* d_ws, size_t ws_size,
                              hipStream_t stream) {
  const float* query = (const float*)d_in[0];
  const float* key   = (const float*)d_in[1];
  const float* value = (const float*)d_in[2];
  const float* spat  = (const float*)d_in[3];
  const float* edge  = (const float*)d_in[4];
  const int*   maskp = (const int*)d_in[5];
  const float* Wq = (const float*)d_in[6];  const float* bq = (const float*)d_in[7];
  const float* Wk = (const float*)d_in[8];  const float* bk = (const float*)d_in[9];
  const float* Wv = (const float*)d_in[10]; const float* bv = (const float*)d_in[11];
  const float* Wo = (const float*)d_in[12]; const float* bo = (const float*)d_in[13];
  float* out = (float*)d_out;

  const int M = BB * TT;  // 8192
  unsigned short* WT3 = (unsigned short*)d_ws;            // [3072][1024] bf16 (Wq,Wk,Wv transposed)
  unsigned short* WoT = WT3 + (size_t)3 * DD * DD;        // [1024][1024]
  unsigned short* QKV = WoT + (size_t)DD * DD;            // [M][3072] bf16
  unsigned short* Vt  = QKV + (size_t)M * QKVLD;          // [B,H,DH,T]
  unsigned short* Obf = Vt + (size_t)M * DD;              // [M][1024] bf16

  convertT4_k<<<2048, 256, 0, stream>>>(Wq, Wk, Wv, Wo, WT3);

  gemm_qkv_k<<<dim3(24, M / 128), 256, 0, stream>>>(query, key, value, WT3, bq, bk, bv, QKV);

  transpose_v_k<<<BB * HH * (TT / 64), 256, 0, stream>>>(QKV, Vt);

  attn_k<<<BB * HH * (TT / 64), 256, 0, stream>>>(QKV, Vt, spat, edge, maskp, Obf);

  gemm_out_k<<<dim3(DD / 128, M / 128), 256, 0, stream>>>(Obf, WoT, bo, out);
}

// Round 11
// 664.732 us; speedup vs baseline: 1.1228x; 1.1228x over previous
//
#include <hip/hip_runtime.h>
#include <hip/hip_bf16.h>

#define BB 8
#define TT 1024
#define DD 1024
#define HH 16
#define DH 64
#define QKVLD 3072

typedef __attribute__((ext_vector_type(8))) short short8;
typedef __attribute__((ext_vector_type(4))) float f32x4;

__device__ __forceinline__ unsigned short f2bf(float f) {
  unsigned int u = __builtin_bit_cast(unsigned int, f);
  unsigned int rounding = 0x7fffu + ((u >> 16) & 1u);
  u += rounding;
  return (unsigned short)(u >> 16);
}
__device__ __forceinline__ float bf2f(unsigned short u) {
  unsigned int x = ((unsigned int)u) << 16;
  return __builtin_bit_cast(float, x);
}

__device__ __forceinline__ void gload16(const void* g, void* l) {
  __builtin_amdgcn_global_load_lds((const __attribute__((address_space(1))) void*)g,
                                   (__attribute__((address_space(3))) void*)l, 16, 0, 0);
}

// ---- fused f32 -> bf16 TRANSPOSING convert of all 4 weights: out[n][k] = bf16(in[k][n]) ----
__global__ __launch_bounds__(256) void convertT4_k(const float* __restrict__ w0,
                                                   const float* __restrict__ w1,
                                                   const float* __restrict__ w2,
                                                   const float* __restrict__ w3,
                                                   unsigned short* __restrict__ out) {
  int bx = blockIdx.x;
  int seg = bx >> 9;
  const float* in = seg == 0 ? w0 : seg == 1 ? w1 : seg == 2 ? w2 : w3;
  unsigned short* o = out + (size_t)seg * DD * DD;
  int g = (bx & 511) * 256 + threadIdx.x;
  int n = g & (DD - 1);
  int kb = (g >> 10) * 8;
  short8 v;
#pragma unroll
  for (int j = 0; j < 8; ++j) v[j] = (short)f2bf(in[(size_t)(kb + j) * DD + n]);
  *(short8*)(o + (size_t)n * DD + kb) = v;
}

// ---------------- fused QKV GEMM: [Q|K|V] = x @ W + b -> bf16 QKV[M][3072] ----------------
__global__ __launch_bounds__(256) void gemm_qkv_k(const float* __restrict__ Aq,
                                                  const float* __restrict__ Ak,
                                                  const float* __restrict__ Av,
                                                  const unsigned short* __restrict__ Wt3,
                                                  const float* __restrict__ bq,
                                                  const float* __restrict__ bk,
                                                  const float* __restrict__ bv,
                                                  unsigned short* __restrict__ C) {
  __shared__ unsigned short Bs[128 * 64];   // swizzled linear, 16KB
  __shared__ unsigned short As[128 * 72];   // padded, 18KB
  const int tid = threadIdx.x, lane = tid & 63, w = tid >> 6;
  const int lo = lane & 15, hi = lane >> 4;
  const int wm = w >> 1, wn = w & 1;
  const int seg = blockIdx.x >> 3;
  const float* Ap = seg == 0 ? Aq : seg == 1 ? Ak : Av;
  const float* bias = seg == 0 ? bq : seg == 1 ? bk : bv;
  const int n0 = blockIdx.x * 128;
  const int m0 = blockIdx.y * 128;
  f32x4 acc[4][4] = {};
  int dmn[4], dmk[4];
#pragma unroll
  for (int i = 0; i < 4; ++i) {
    int d = i * 4096 + w * 1024 + lane * 16;
    int lz = d ^ (((d >> 7) & 7) << 4);
    dmn[i] = d >> 7;
    dmk[i] = (lz & 127) >> 1;
  }
  for (int k0 = 0; k0 < DD; k0 += 64) {
#pragma unroll
    for (int i = 0; i < 4; ++i)
      gload16(Wt3 + (size_t)(n0 + dmn[i]) * DD + k0 + dmk[i], &Bs[(i * 4096 + w * 1024) >> 1]);
#pragma unroll
    for (int it = 0; it < 4; ++it) {
      int c = tid + 256 * it;
      int r = c >> 3, cb = (c & 7) * 8;
      const float* src = Ap + (size_t)(m0 + r) * DD + k0 + cb;
      float4 v0 = *(const float4*)src;
      float4 v1 = *(const float4*)(src + 4);
      short8 sv;
      sv[0] = (short)f2bf(v0.x); sv[1] = (short)f2bf(v0.y);
      sv[2] = (short)f2bf(v0.z); sv[3] = (short)f2bf(v0.w);
      sv[4] = (short)f2bf(v1.x); sv[5] = (short)f2bf(v1.y);
      sv[6] = (short)f2bf(v1.z); sv[7] = (short)f2bf(v1.w);
      *(short8*)&As[r * 72 + cb] = sv;
    }
    __syncthreads();
#pragma unroll
    for (int s = 0; s < 2; ++s) {
      short8 af[4], bf[4];
#pragma unroll
      for (int mt = 0; mt < 4; ++mt)
        af[mt] = *(const short8*)&As[(wm * 64 + mt * 16 + lo) * 72 + s * 32 + hi * 8];
#pragma unroll
      for (int nt = 0; nt < 4; ++nt) {
        int nr = wn * 64 + nt * 16 + lo;
        int byte = (nr * 128 + s * 64 + hi * 16) ^ ((nr & 7) << 4);
        bf[nt] = *(const short8*)((const char*)Bs + byte);
      }
#pragma unroll
      for (int mt = 0; mt < 4; ++mt)
#pragma unroll
        for (int nt = 0; nt < 4; ++nt)
          acc[mt][nt] = __builtin_amdgcn_mfma_f32_16x16x32_bf16(af[mt], bf[nt], acc[mt][nt], 0, 0, 0);
    }
    __syncthreads();
  }
#pragma unroll
  for (int mt = 0; mt < 4; ++mt)
#pragma unroll
    for (int nt = 0; nt < 4; ++nt) {
      int cl = wn * 64 + nt * 16 + lo;
      float bvv = bias[(n0 & 1023) + cl];
      int col = n0 + cl;
#pragma unroll
      for (int r = 0; r < 4; ++r) {
        int row = m0 + wm * 64 + mt * 16 + hi * 4 + r;
        C[(size_t)row * QKVLD + col] = f2bf(acc[mt][nt][r] + bvv);
      }
    }
}

// ---------------- output GEMM: out = Obf @ Wo + bo (f32 out), A and B both DMA-staged ----------------
__global__ __launch_bounds__(256) void gemm_out_k(const unsigned short* __restrict__ Aobf,
                                                  const unsigned short* __restrict__ WoT,
                                                  const float* __restrict__ bo,
                                                  float* __restrict__ out) {
  __shared__ unsigned short Bs[128 * 64];
  __shared__ unsigned short As[128 * 64];
  const int tid = threadIdx.x, lane = tid & 63, w = tid >> 6;
  const int lo = lane & 15, hi = lane >> 4;
  const int wm = w >> 1, wn = w & 1;
  const int n0 = blockIdx.x * 128;
  const int m0 = blockIdx.y * 128;
  f32x4 acc[4][4] = {};
  int dmn[4], dmk[4];
#pragma unroll
  for (int i = 0; i < 4; ++i) {
    int d = i * 4096 + w * 1024 + lane * 16;
    int lz = d ^ (((d >> 7) & 7) << 4);
    dmn[i] = d >> 7;
    dmk[i] = (lz & 127) >> 1;
  }
  for (int k0 = 0; k0 < DD; k0 += 64) {
#pragma unroll
    for (int i = 0; i < 4; ++i) {
      gload16(WoT + (size_t)(n0 + dmn[i]) * DD + k0 + dmk[i], &Bs[(i * 4096 + w * 1024) >> 1]);
      gload16(Aobf + (size_t)(m0 + dmn[i]) * DD + k0 + dmk[i], &As[(i * 4096 + w * 1024) >> 1]);
    }
    __syncthreads();
#pragma unroll
    for (int s = 0; s < 2; ++s) {
      short8 af[4], bf[4];
#pragma unroll
      for (int mt = 0; mt < 4; ++mt) {
        int mr = wm * 64 + mt * 16 + lo;
        int byte = (mr * 128 + s * 64 + hi * 16) ^ ((mr & 7) << 4);
        af[mt] = *(const short8*)((const char*)As + byte);
      }
#pragma unroll
      for (int nt = 0; nt < 4; ++nt) {
        int nr = wn * 64 + nt * 16 + lo;
        int byte = (nr * 128 + s * 64 + hi * 16) ^ ((nr & 7) << 4);
        bf[nt] = *(const short8*)((const char*)Bs + byte);
      }
#pragma unroll
      for (int mt = 0; mt < 4; ++mt)
#pragma unroll
        for (int nt = 0; nt < 4; ++nt)
          acc[mt][nt] = __builtin_amdgcn_mfma_f32_16x16x32_bf16(af[mt], bf[nt], acc[mt][nt], 0, 0, 0);
    }
    __syncthreads();
  }
#pragma unroll
  for (int mt = 0; mt < 4; ++mt)
#pragma unroll
    for (int nt = 0; nt < 4; ++nt) {
      int col = n0 + wn * 64 + nt * 16 + lo;
      float bvv = bo[col];
#pragma unroll
      for (int r = 0; r < 4; ++r) {
        int row = m0 + wm * 64 + mt * 16 + hi * 4 + r;
        out[(size_t)row * DD + col] = acc[mt][nt][r] + bvv;
      }
    }
}

// ------------- V transpose per head from QKV: -> (B,H,DH,T) -------------
__global__ __launch_bounds__(256) void transpose_v_k(const unsigned short* __restrict__ QKV,
                                                     unsigned short* __restrict__ Vt) {
  __shared__ unsigned short tile[64][72];
  const int blk = blockIdx.x;
  const int t0 = (blk & 15) * 64;
  const int h = (blk >> 4) & 15;
  const int b = blk >> 8;
  const int tid = threadIdx.x;
#pragma unroll
  for (int it = 0; it < 2; ++it) {
    int c = tid + 256 * it;
    int r = c >> 3, d8 = (c & 7) * 8;
    short8 v = *(const short8*)(QKV + ((size_t)(b * TT + t0 + r)) * QKVLD + 2048 + h * DH + d8);
    *(short8*)&tile[r][d8] = v;
  }
  __syncthreads();
#pragma unroll
  for (int it = 0; it < 2; ++it) {
    int c = tid + 256 * it;
    int d = c >> 3, t8 = (c & 7) * 8;
    short8 o;
#pragma unroll
    for (int j = 0; j < 8; ++j) o[j] = (short)tile[t8 + j][d];
    *(short8*)(Vt + ((size_t)(b * HH + h) * DH + d) * TT + t0 + t8) = o;
  }
}

// ---------------- flash attention, KVBLK=64, DMA-prefetched bias in LDS ----------------
// 4 waves; wave w owns 16 q-rows. Bias (spatial+edge) double-buffered via global_load_lds:
// stage tile t+1 -> compute tile t (softmax reads LDS) -> __syncthreads (drains DMA).
__global__ __launch_bounds__(256) void attn_k(const unsigned short* __restrict__ QKV,
                                              const unsigned short* __restrict__ Vt,
                                              const float* __restrict__ spat,
                                              const float* __restrict__ edge,
                                              const int* __restrict__ mask,
                                              unsigned short* __restrict__ Obf) {
  __shared__ float SB[2][2][4][16][64];     // [dbuf][s/e][wave][q16][k64] = 64KB
  __shared__ unsigned short P[4][16][72];   // 9.2KB, wave-private
  const int blk = blockIdx.x;
  const int qt = blk & 15;
  const int h = (blk >> 4) & 15;
  const int b = blk >> 8;
  const int tid = threadIdx.x;
  const int w = tid >> 6;
  const int lane = tid & 63;
  const int lo = lane & 15, hi = lane >> 4;
  const int q0 = qt * 64 + w * 16;

  const unsigned short* Qb = QKV + ((size_t)(b * TT + q0)) * QKVLD + h * DH;
  const unsigned short* Kb = QKV + (size_t)b * TT * QKVLD + 1024 + h * DH;
  const unsigned short* Vb = Vt + (size_t)(b * HH + h) * DH * TT;
  const int* Mk = mask + b * TT;
  // per-lane global source for bias DMA: row (q0 + lane>>4), col (lane&15)*4 floats
  const float* SpW = spat + (size_t)b * TT * TT + (size_t)(q0 + (lane >> 4)) * TT + (lane & 15) * 4;
  const float* EdW = edge + (size_t)b * TT * TT + (size_t)(q0 + (lane >> 4)) * TT + (lane & 15) * 4;

#define STAGE(bf, kk)                                              \
  do {                                                             \
    _Pragma("unroll") for (int i_ = 0; i_ < 4; ++i_) {             \
      gload16(SpW + (size_t)i_ * 4 * TT + (kk), &SB[bf][0][w][i_ * 4][0]); \
      gload16(EdW + (size_t)i_ * 4 * TT + (kk), &SB[bf][1][w][i_ * 4][0]); \
    }                                                              \
  } while (0)

  // Q fragments, pre-scaled by 1/sqrt(DH)=0.125 (exact exponent shift in bf16)
  short8 qf0, qf1;
  {
    short8 qr0 = *(const short8*)(Qb + (size_t)lo * QKVLD + hi * 8);
    short8 qr1 = *(const short8*)(Qb + (size_t)lo * QKVLD + 32 + hi * 8);
#pragma unroll
    for (int j = 0; j < 8; ++j) {
      qf0[j] = (short)f2bf(bf2f((unsigned short)qr0[j]) * 0.125f);
      qf1[j] = (short)f2bf(bf2f((unsigned short)qr1[j]) * 0.125f);
    }
  }

  float m[4], l[4];
  f32x4 acc[4] = {};
#pragma unroll
  for (int r = 0; r < 4; ++r) { m[r] = -INFINITY; l[r] = 0.f; }

  STAGE(0, 0);
  __syncthreads();

  for (int t = 0; t < 16; ++t) {
    const int k0 = t * 64;
    const int cur = t & 1;
    if (t < 15) STAGE(cur ^ 1, k0 + 64);   // prefetch next tile while computing this one

    short8 kf[8];
#pragma unroll
    for (int kt = 0; kt < 4; ++kt) {
      const unsigned short* kp = Kb + (size_t)(k0 + kt * 16 + lo) * QKVLD + hi * 8;
      kf[kt * 2] = *(const short8*)kp;
      kf[kt * 2 + 1] = *(const short8*)(kp + 32);
    }
    int mk[4];
#pragma unroll
    for (int kt = 0; kt < 4; ++kt) mk[kt] = Mk[k0 + kt * 16 + lo];

    f32x4 sc[4];
#pragma unroll
    for (int kt = 0; kt < 4; ++kt) {
      f32x4 z = {};
      z = __builtin_amdgcn_mfma_f32_16x16x32_bf16(qf0, kf[kt * 2], z, 0, 0, 0);
      sc[kt] = __builtin_amdgcn_mfma_f32_16x16x32_bf16(qf1, kf[kt * 2 + 1], z, 0, 0, 0);
    }

    float alpha[4];
#pragma unroll
    for (int r = 0; r < 4; ++r) {
      const float* srow = &SB[cur][0][w][hi * 4 + r][0];
      const float* erow = &SB[cur][1][w][hi * 4 + r][0];
      float s[4];
#pragma unroll
      for (int j = 0; j < 4; ++j) {
        float bb = mk[j] ? -1e30f : (srow[j * 16 + lo] + erow[j * 16 + lo]);
        s[j] = sc[j][r] + bb;
      }
      float mx = fmaxf(fmaxf(s[0], s[1]), fmaxf(s[2], s[3]));
      mx = fmaxf(mx, __shfl_xor(mx, 1));
      mx = fmaxf(mx, __shfl_xor(mx, 2));
      mx = fmaxf(mx, __shfl_xor(mx, 4));
      mx = fmaxf(mx, __shfl_xor(mx, 8));
      float mn = fmaxf(m[r], mx);
      alpha[r] = __expf(m[r] - mn);
      m[r] = mn;
      float rs = 0.f;
#pragma unroll
      for (int j = 0; j < 4; ++j) {
        s[j] = __expf(s[j] - mn);
        rs += s[j];
        P[w][hi * 4 + r][j * 16 + lo] = f2bf(s[j]);
      }
      rs += __shfl_xor(rs, 1);
      rs += __shfl_xor(rs, 2);
      rs += __shfl_xor(rs, 4);
      rs += __shfl_xor(rs, 8);
      l[r] = l[r] * alpha[r] + rs;
    }
#pragma unroll
    for (int dt = 0; dt < 4; ++dt)
#pragma unroll
      for (int r = 0; r < 4; ++r) acc[dt][r] *= alpha[r];

#pragma unroll
    for (int kc = 0; kc < 2; ++kc) {
      short8 pf = *(const short8*)&P[w][lo][kc * 32 + hi * 8];
#pragma unroll
      for (int dt = 0; dt < 4; ++dt) {
        short8 vf = *(const short8*)(Vb + (size_t)(dt * 16 + lo) * TT + k0 + kc * 32 + hi * 8);
        acc[dt] = __builtin_amdgcn_mfma_f32_16x16x32_bf16(pf, vf, acc[dt], 0, 0, 0);
      }
    }
    __syncthreads();   // drains prefetch DMAs + guards dbuf reuse
  }
#undef STAGE

  float rl[4];
#pragma unroll
  for (int r = 0; r < 4; ++r) rl[r] = 1.0f / l[r];
  unsigned short* Ob = Obf + ((size_t)b * TT + q0) * DD + h * DH;
#pragma unroll
  for (int dt = 0; dt < 4; ++dt)
#pragma unroll
    for (int r = 0; r < 4; ++r)
      Ob[(size_t)(hi * 4 + r) * DD + dt * 16 + lo] = f2bf(acc[dt][r] * rl[r]);
}

extern "C" void kernel_launch(void* const* d_in, const int* in_sizes, int n_in,
                              void* d_out, int out_size, void* d_ws, size_t ws_size,
                              hipStream_t stream) {
  const float* query = (const float*)d_in[0];
  const float* key   = (const float*)d_in[1];
  const float* value = (const float*)d_in[2];
  const float* spat  = (const float*)d_in[3];
  const float* edge  = (const float*)d_in[4];
  const int*   maskp = (const int*)d_in[5];
  const float* Wq = (const float*)d_in[6];  const float* bq = (const float*)d_in[7];
  const float* Wk = (const float*)d_in[8];  const float* bk = (const float*)d_in[9];
  const float* Wv = (const float*)d_in[10]; const float* bv = (const float*)d_in[11];
  const float* Wo = (const float*)d_in[12]; const float* bo = (const float*)d_in[13];
  float* out = (float*)d_out;

  const int M = BB * TT;  // 8192
  unsigned short* WT3 = (unsigned short*)d_ws;            // [3072][1024] bf16
  unsigned short* WoT = WT3 + (size_t)3 * DD * DD;        // [1024][1024]
  unsigned short* QKV = WoT + (size_t)DD * DD;            // [M][3072] bf16
  unsigned short* Vt  = QKV + (size_t)M * QKVLD;          // [B,H,DH,T]
  unsigned short* Obf = Vt + (size_t)M * DD;              // [M][1024] bf16

  convertT4_k<<<2048, 256, 0, stream>>>(Wq, Wk, Wv, Wo, WT3);

  gemm_qkv_k<<<dim3(24, M / 128), 256, 0, stream>>>(query, key, value, WT3, bq, bk, bv, QKV);

  transpose_v_k<<<BB * HH * (TT / 64), 256, 0, stream>>>(QKV, Vt);

  attn_k<<<BB * HH * (TT / 64), 256, 0, stream>>>(QKV, Vt, spat, edge, maskp, Obf);

  gemm_out_k<<<dim3(DD / 128, M / 128), 256, 0, stream>>>(Obf, WoT, bo, out);
}